// Round 10
// baseline (99.355 us; speedup 1.0000x reference)
//
#include <hip/hip_runtime.h>
#include <hip/hip_bf16.h>
#include <stdint.h>

// ---- types ----
typedef __attribute__((ext_vector_type(4)))  int   i32x4;
typedef __attribute__((ext_vector_type(8)))  int   i32x8;
typedef __attribute__((ext_vector_type(16))) float f32x16;

typedef const void __attribute__((address_space(1)))* gas_ptr;
typedef void __attribute__((address_space(3)))* las_ptr;
#define GLD16(g, l) __builtin_amdgcn_global_load_lds((gas_ptr)(g), (las_ptr)(l), 16, 0, 0)

// ---- problem sizes ----
#define NIMG 32
#define CIN  256
#define HWDIM 56
#define HPAD 58
#define OCH  256
#define SPATIAL (HWDIM*HWDIM)        // 3136
#define M_TOT (NIMG*SPATIAL)         // 100352
#define KTOT  2304                    // 9*256
#define NSTEP 36                      // K-steps of 64 (fp4 nibbles)
#define ROWB  128                     // bytes per padded spatial position (256c/2)
#define WROWB 1152                    // bytes per o-row of WT4 (2304 nibbles)

// workspace layout (bytes)
#define WT4_OFF   13778944ull         // after xb4: 32*58*58*128
#define ALPHA_OFF 14073856ull         // after WT4: 256*1152

#define LDSBUF 8192                   // W 128x32B (4KB) + A 128x32B (4KB)

// =====================================================================
// Kernel 1: per-o alpha + ternary fp4(e2m1) weights, transposed+packed:
// WT4[o][byte i] = nibbles for k=2i (low), k=2i+1 (high); k = tap*256 + c
// =====================================================================
__global__ __launch_bounds__(256)
void prep_weights(const float* __restrict__ w1, const float* __restrict__ w2,
                  unsigned char* __restrict__ WT4, float* __restrict__ alpha) {
    const int o = blockIdx.x;
    const int t = threadIdx.x;
    const float* p1 = w1 + o * KTOT;
    const float* p2 = w2 + o * KTOT;
    unsigned char* wo = WT4 + o * WROWB;

    float s1 = 0.f, s2 = 0.f;
    for (int i = t; i < WROWB; i += 256) {
        int k0  = 2 * i;
        int tap = k0 >> 8;            // k = tap*256 + c
        int c   = k0 & 255;           // even
        float a0 = p1[c * 9 + tap],       b0 = p2[c * 9 + tap];
        float a1 = p1[(c + 1) * 9 + tap], b1 = p2[(c + 1) * 9 + tap];
        s1 += fabsf(a0) + fabsf(a1);
        s2 += fabsf(b0) + fabsf(b1);
        int sg0 = ((a0 > 0.f) - (a0 < 0.f)) + ((b0 > 0.f) - (b0 < 0.f));
        int sg1 = ((a1 > 0.f) - (a1 < 0.f)) + ((b1 > 0.f) - (b1 < 0.f));
        // fp4 e2m1: +1=0x2 +2=0x4 -1=0xA -2=0xC 0=0x0
        unsigned e0 = (sg0 == 2) ? 0x4u : (sg0 == 1) ? 0x2u : (sg0 == 0) ? 0x0u
                    : (sg0 == -1) ? 0xAu : 0xCu;
        unsigned e1 = (sg1 == 2) ? 0x4u : (sg1 == 1) ? 0x2u : (sg1 == 0) ? 0x0u
                    : (sg1 == -1) ? 0xAu : 0xCu;
        wo[i] = (unsigned char)(e0 | (e1 << 4));
    }
    __shared__ float red[8];
    #pragma unroll
    for (int off = 32; off > 0; off >>= 1) {
        s1 += __shfl_down(s1, off, 64);
        s2 += __shfl_down(s2, off, 64);
    }
    const int lane = t & 63, wv = t >> 6;
    if (lane == 0) { red[wv] = s1; red[4 + wv] = s2; }
    __syncthreads();
    if (t == 0) {
        float t1 = red[0] + red[1] + red[2] + red[3];
        float t2 = red[4] + red[5] + red[6] + red[7];
        alpha[o] = (t1 * (1.f / 2304.f) + t2 * (1.f / 2304.f)) * 0.5f;
    }
}

// =====================================================================
// Kernel 2: binarize x to fp4 nibbles + NCHW -> padded NHWC(/2B), with
// border zeroing. Grid = 32 * 58 blocks: one per (n, hp).
// =====================================================================
__global__ __launch_bounds__(256)
void binarize_kernel(const float* __restrict__ x, unsigned char* __restrict__ xb4) {
    const int b  = blockIdx.x;
    const int n  = b / HPAD;
    const int hp = b % HPAD;
    const int t  = threadIdx.x;
    unsigned char* rowp = xb4 + ((size_t)n * HPAD + hp) * (HPAD * ROWB);

    if (hp == 0 || hp == HPAD - 1) {
        int* ip = (int*)rowp;                 // 58*128 B = 1856 ints
        for (int i = t; i < 1856; i += 256) ip[i] = 0;
        return;
    }
    const int h = hp - 1;
    __shared__ __align__(4) unsigned char tile[HWDIM * 132];  // [w][128B], pad 132
    if (t < 224) {
        const int w  = t % HWDIM;
        const int cl = t / HWDIM;             // 0..3
        const float* xp = x + (size_t)n * (CIN * SPATIAL) + (size_t)h * HWDIM + w;
        for (int c0 = cl * 2; c0 < CIN; c0 += 8) {
            float v0 = xp[(size_t)c0 * SPATIAL];
            float v1 = xp[(size_t)(c0 + 1) * SPATIAL];
            unsigned e0 = (v0 > 0.f) ? 0x2u : ((v0 < 0.f) ? 0xAu : 0x0u);
            unsigned e1 = (v1 > 0.f) ? 0x2u : ((v1 < 0.f) ? 0xAu : 0x0u);
            tile[w * 132 + (c0 >> 1)] = (unsigned char)(e0 | (e1 << 4));
        }
    }
    // zero left/right pad columns of this row
    int* ip = (int*)rowp;
    if (t < 32) ip[t] = 0;                     // w = 0
    else if (t < 64) ip[57 * 32 + (t - 32)] = 0; // w = 57
    __syncthreads();
    // drain: 8 lane-groups of 32; group g writes w = w0+g, 128B coalesced
    const int g = t >> 5, lam = t & 31;
    unsigned char* op = rowp + ROWB;           // w starts at 1
    for (int w0 = 0; w0 < HWDIM; w0 += 8) {
        int w = w0 + g;
        int val = *(const int*)&tile[w * 132 + lam * 4];
        *(int*)(op + (size_t)w * ROWB + lam * 4) = val;
    }
}

// =====================================================================
// Kernel 3: MX-fp4 implicit-GEMM. Block = 128(o) x 128(sp), 4 waves in a
// 2x2 grid, wave = 64x64 (acc[2][2] of 32x32 = 64 AccVGPR; combined regs
// fit 128 -> 4 waves/SIMD, 16 waves/CU, 4 blocks/CU: 2x r9's occupancy,
// attacking the measured per-step serialization wall).
// Ring-3 LDS (24KB), homogeneous GLD16 stream, counted vmcnt(2),
// 1 barrier/step. Both-sides slot swizzle slot'=((r<<1)|h)^(r&7):
// conflict-free reads (all 8 bank positions per 8-row group).
// =====================================================================
__global__ __launch_bounds__(256, 4)
void conv_kernel(const unsigned char* __restrict__ xb4,
                 const unsigned char* __restrict__ WT4,
                 const float* __restrict__ alpha,
                 float* __restrict__ out) {
    __shared__ __align__(16) char lds[3 * LDSBUF];

    const int t    = threadIdx.x;
    const int lane = t & 63;
    const int wv   = t >> 6;

    // XCD-aware bijective remap: 1568 blocks = 8 XCDs * 196
    const int bid  = blockIdx.x;
    const int tid_ = (bid & 7) * 196 + (bid >> 3);
    const int nt   = tid_ & 1;        // o-tile (0/1)
    const int mt   = tid_ >> 1;       // sp-tile (0..783)
    const int o0   = nt * 128;
    const int m0   = mt * 128;

    // ---- staging decode: thread t fills LDS slot t; inverse-swizzle picks
    // which (subtile, row, half) belongs there: slot6 = ((r<<1)|h)^(r&7).
    int st, srow, sh;
    {
        const int s6 = t & 63;
        st = t >> 6;                          // 32-row subtile 0..3
        int r2 = (s6 >> 3) & 1, r3 = (s6 >> 4) & 1, r4 = (s6 >> 5) & 1;
        int r1 = ((s6 >> 2) & 1) ^ r2;
        int r0 = ((s6 >> 1) & 1) ^ r1;
        sh = (s6 & 1) ^ r0;                   // 16B half 0/1
        srow = r0 | (r1 << 1) | (r2 << 2) | (r3 << 3) | (r4 << 4);
    }
    const unsigned char* w_g = WT4 + (size_t)(o0 + st * 32 + srow) * WROWB + sh * 16;
    const unsigned char* a_g;
    {
        int m  = m0 + st * 32 + srow;
        int ni = m / SPATIAL;
        int sp = m - ni * SPATIAL;
        int h  = sp / HWDIM;
        int w  = sp - h * HWDIM;
        a_g = xb4 + ((size_t)(ni * HPAD + h) * HPAD + w) * ROWB + sh * 16;
    }
    char* dstT = lds + t * 16;

    f32x16 acc[2][2];
    #pragma unroll
    for (int i = 0; i < 2; ++i)
        #pragma unroll
        for (int j = 0; j < 2; ++j)
            acc[i][j] = (f32x16){0.f,0.f,0.f,0.f,0.f,0.f,0.f,0.f,
                                 0.f,0.f,0.f,0.f,0.f,0.f,0.f,0.f};

    // ---- read-side: lane (row l31, half l5), swizzled slot within subtile
    const int l31 = lane & 31;
    const int l5  = lane >> 5;
    const int fro  = ((((l31 << 1) | l5) ^ (l31 & 7)) << 4);
    const int wsel = (wv & 1) * 2048;         // wave's 64-o slice (2 subtiles)
    const int asel = 4096 + (wv >> 1) * 2048; // wave's 64-sp slice

    #define STAGE(S, B)                                                     \
    {                                                                       \
        const int s_ = (S);                                                 \
        const int tap = s_ >> 2;                                            \
        const int kh = tap / 3, kw = tap - kh * 3;                          \
        const int aoff = (kh * HPAD + kw) * ROWB + (s_ & 3) * 32;           \
        const int woff = s_ * 32;                                           \
        char* d = dstT + (B) * LDSBUF;                                      \
        GLD16(w_g + woff, d);                                               \
        GLD16(a_g + aoff, d + 4096);                                        \
    }

    i32x8 wf[2] = {};
    i32x8 xf[2] = {};

    // prologue: stage 0,1 (4 loads); drain stage 0 (2 younger); barrier
    STAGE(0, 0);
    STAGE(1, 1);
    asm volatile("s_waitcnt vmcnt(2)\n\ts_barrier" ::: "memory");

    #pragma unroll
    for (int s = 0; s < NSTEP; ++s) {
        const char* Wb = lds + (s % 3) * LDSBUF;

        if (s + 2 < NSTEP) STAGE(s + 2, (s + 2) % 3);   // 2 DMA

        #pragma unroll
        for (int i = 0; i < 2; ++i)
            *(i32x4*)&wf[i] = *(const i32x4*)(Wb + wsel + i * 1024 + fro);
        #pragma unroll
        for (int j = 0; j < 2; ++j)
            *(i32x4*)&xf[j] = *(const i32x4*)(Wb + asel + j * 1024 + fro);

        __builtin_amdgcn_s_setprio(1);
        #pragma unroll
        for (int i = 0; i < 2; ++i)
            #pragma unroll
            for (int j = 0; j < 2; ++j)
                acc[i][j] = __builtin_amdgcn_mfma_scale_f32_32x32x64_f8f6f4(
                    wf[i], xf[j], acc[i][j], 4, 4, 0, 127, 0, 127);
        __builtin_amdgcn_s_setprio(0);

        // end-of-step: stage s+1 retired (2 younger DMA), reads drained, barrier
        if (s < NSTEP - 2)
            asm volatile("s_waitcnt vmcnt(2) lgkmcnt(0)\n\ts_barrier" ::: "memory");
        else if (s == NSTEP - 2)
            asm volatile("s_waitcnt vmcnt(0) lgkmcnt(0)\n\ts_barrier" ::: "memory");
    }

    // ---- epilogue: out[n][o][h][w] = acc * alpha[o] ----
    // 32x32 D frag: col(sp) = lane&31, row(o) = (reg&3)+8*(reg>>2)+4*(lane>>5)
    const int ob0 = o0 + (wv & 1) * 64;
    const int mb0 = m0 + (wv >> 1) * 64;
    #pragma unroll
    for (int j = 0; j < 2; ++j) {
        int m  = mb0 + j * 32 + l31;
        int ni = m / SPATIAL;
        int sp = m - ni * SPATIAL;
        long base = (long)ni * (OCH * SPATIAL) + sp;
        #pragma unroll
        for (int i = 0; i < 2; ++i) {
            #pragma unroll
            for (int r = 0; r < 16; ++r) {
                int o = ob0 + i * 32 + (r & 3) + 8 * (r >> 2) + 4 * l5;
                out[base + (long)o * SPATIAL] = acc[i][j][r] * alpha[o];
            }
        }
    }
    #undef STAGE
}

// =====================================================================
extern "C" void kernel_launch(void* const* d_in, const int* in_sizes, int n_in,
                              void* d_out, int out_size, void* d_ws, size_t ws_size,
                              hipStream_t stream) {
    const float* x  = (const float*)d_in[0];
    const float* w1 = (const float*)d_in[1];
    const float* w2 = (const float*)d_in[2];
    float* out = (float*)d_out;

    char* ws = (char*)d_ws;
    unsigned char* xb4   = (unsigned char*)ws;
    unsigned char* WT4   = (unsigned char*)(ws + WT4_OFF);
    float*         alpha = (float*)(ws + ALPHA_OFF);

    hipLaunchKernelGGL(prep_weights, dim3(OCH), dim3(256), 0, stream, w1, w2, WT4, alpha);
    hipLaunchKernelGGL(binarize_kernel, dim3(NIMG * HPAD), dim3(256), 0, stream, x, xb4);
    hipLaunchKernelGGL(conv_kernel, dim3((M_TOT / 128) * 2), dim3(256), 0, stream,
                       xb4, WT4, alpha, out);
}

// Round 11
// 81.286 us; speedup vs baseline: 1.2223x; 1.2223x over previous
//
#include <hip/hip_runtime.h>
#include <hip/hip_bf16.h>
#include <stdint.h>

// ---- types ----
typedef __attribute__((ext_vector_type(4)))  int   i32x4;
typedef __attribute__((ext_vector_type(8)))  int   i32x8;
typedef __attribute__((ext_vector_type(16))) float f32x16;

typedef const void __attribute__((address_space(1)))* gas_ptr;
typedef void __attribute__((address_space(3)))* las_ptr;
#define GLD16(g, l) __builtin_amdgcn_global_load_lds((gas_ptr)(g), (las_ptr)(l), 16, 0, 0)

// ---- problem sizes ----
#define NIMG 32
#define CIN  256
#define HWDIM 56
#define HPAD 58
#define OCH  256
#define SPATIAL (HWDIM*HWDIM)        // 3136
#define M_TOT (NIMG*SPATIAL)         // 100352
#define KTOT  2304                    // 9*256
#define NSTEP 18                      // K-steps of 128 (fp4 nibbles, 64B)
#define ROWB  128                     // bytes per padded spatial position (256c/2)
#define WROWB 1152                    // bytes per o-row of WT4 (2304 nibbles)

// workspace layout (bytes)
#define WT4_OFF   13778944ull         // after xb4: 32*58*58*128
#define ALPHA_OFF 14073856ull         // after WT4: 256*1152

#define LDSBUF 16384                  // W 128x64B (8KB) + A 128x64B (8KB)

// =====================================================================
// Kernel 1: per-o alpha + ternary fp4(e2m1) weights, transposed+packed:
// WT4[o][byte i] = nibbles for k=2i (low), k=2i+1 (high); k = tap*256 + c
// =====================================================================
__global__ __launch_bounds__(256)
void prep_weights(const float* __restrict__ w1, const float* __restrict__ w2,
                  unsigned char* __restrict__ WT4, float* __restrict__ alpha) {
    const int o = blockIdx.x;
    const int t = threadIdx.x;
    const float* p1 = w1 + o * KTOT;
    const float* p2 = w2 + o * KTOT;
    unsigned char* wo = WT4 + o * WROWB;

    float s1 = 0.f, s2 = 0.f;
    for (int i = t; i < WROWB; i += 256) {
        int k0  = 2 * i;
        int tap = k0 >> 8;            // k = tap*256 + c
        int c   = k0 & 255;           // even
        float a0 = p1[c * 9 + tap],       b0 = p2[c * 9 + tap];
        float a1 = p1[(c + 1) * 9 + tap], b1 = p2[(c + 1) * 9 + tap];
        s1 += fabsf(a0) + fabsf(a1);
        s2 += fabsf(b0) + fabsf(b1);
        int sg0 = ((a0 > 0.f) - (a0 < 0.f)) + ((b0 > 0.f) - (b0 < 0.f));
        int sg1 = ((a1 > 0.f) - (a1 < 0.f)) + ((b1 > 0.f) - (b1 < 0.f));
        // fp4 e2m1: +1=0x2 +2=0x4 -1=0xA -2=0xC 0=0x0
        unsigned e0 = (sg0 == 2) ? 0x4u : (sg0 == 1) ? 0x2u : (sg0 == 0) ? 0x0u
                    : (sg0 == -1) ? 0xAu : 0xCu;
        unsigned e1 = (sg1 == 2) ? 0x4u : (sg1 == 1) ? 0x2u : (sg1 == 0) ? 0x0u
                    : (sg1 == -1) ? 0xAu : 0xCu;
        wo[i] = (unsigned char)(e0 | (e1 << 4));
    }
    __shared__ float red[8];
    #pragma unroll
    for (int off = 32; off > 0; off >>= 1) {
        s1 += __shfl_down(s1, off, 64);
        s2 += __shfl_down(s2, off, 64);
    }
    const int lane = t & 63, wv = t >> 6;
    if (lane == 0) { red[wv] = s1; red[4 + wv] = s2; }
    __syncthreads();
    if (t == 0) {
        float t1 = red[0] + red[1] + red[2] + red[3];
        float t2 = red[4] + red[5] + red[6] + red[7];
        alpha[o] = (t1 * (1.f / 2304.f) + t2 * (1.f / 2304.f)) * 0.5f;
    }
}

// =====================================================================
// Kernel 2: binarize x to fp4 nibbles + NCHW -> padded NHWC(/2B), with
// border zeroing. Grid = 32 * 58 blocks: one per (n, hp).
// =====================================================================
__global__ __launch_bounds__(256)
void binarize_kernel(const float* __restrict__ x, unsigned char* __restrict__ xb4) {
    const int b  = blockIdx.x;
    const int n  = b / HPAD;
    const int hp = b % HPAD;
    const int t  = threadIdx.x;
    unsigned char* rowp = xb4 + ((size_t)n * HPAD + hp) * (HPAD * ROWB);

    if (hp == 0 || hp == HPAD - 1) {
        int* ip = (int*)rowp;                 // 58*128 B = 1856 ints
        for (int i = t; i < 1856; i += 256) ip[i] = 0;
        return;
    }
    const int h = hp - 1;
    __shared__ __align__(4) unsigned char tile[HWDIM * 132];  // [w][128B], pad 132
    if (t < 224) {
        const int w  = t % HWDIM;
        const int cl = t / HWDIM;             // 0..3
        const float* xp = x + (size_t)n * (CIN * SPATIAL) + (size_t)h * HWDIM + w;
        for (int c0 = cl * 2; c0 < CIN; c0 += 8) {
            float v0 = xp[(size_t)c0 * SPATIAL];
            float v1 = xp[(size_t)(c0 + 1) * SPATIAL];
            unsigned e0 = (v0 > 0.f) ? 0x2u : ((v0 < 0.f) ? 0xAu : 0x0u);
            unsigned e1 = (v1 > 0.f) ? 0x2u : ((v1 < 0.f) ? 0xAu : 0x0u);
            tile[w * 132 + (c0 >> 1)] = (unsigned char)(e0 | (e1 << 4));
        }
    }
    // zero left/right pad columns of this row
    int* ip = (int*)rowp;
    if (t < 32) ip[t] = 0;                     // w = 0
    else if (t < 64) ip[57 * 32 + (t - 32)] = 0; // w = 57
    __syncthreads();
    // drain: 8 lane-groups of 32; group g writes w = w0+g, 128B coalesced
    const int g = t >> 5, lam = t & 31;
    unsigned char* op = rowp + ROWB;           // w starts at 1
    for (int w0 = 0; w0 < HWDIM; w0 += 8) {
        int w = w0 + g;
        int val = *(const int*)&tile[w * 132 + lam * 4];
        *(int*)(op + (size_t)w * ROWB + lam * 4) = val;
    }
}

// =====================================================================
// Kernel 3: MX-fp4 implicit-GEMM, K=128 steps (18 total). Block = 128(o)
// x 128(sp), 4 waves 2x2, wave = 64x64 (acc[2][2] of 32x32).
// COALESCED staging: A staged as 64B halves of contiguous 128B position
// rows (lines fully used, sequential); W as 64B chunks of o-rows.
// DMA instrs per staged byte cut 4x vs r10 (the TA-scatter wall).
// Ring-3 LDS (48KB -> 3 blocks/CU, 12 waves), homogeneous GLD16 stream,
// counted vmcnt(4), 1 barrier/step. Both-sides slot swizzle within 64B
// rows: slot' = slot ^ (row&3) -> uniform 8 accesses/bank (= b128
// conflict-free baseline).
// =====================================================================
__global__ __launch_bounds__(256, 3)
void conv_kernel(const unsigned char* __restrict__ xb4,
                 const unsigned char* __restrict__ WT4,
                 const float* __restrict__ alpha,
                 float* __restrict__ out) {
    __shared__ __align__(16) char lds[3 * LDSBUF];

    const int t    = threadIdx.x;
    const int lane = t & 63;
    const int wv   = t >> 6;

    // XCD-aware bijective remap: 1568 blocks = 8 XCDs * 196
    const int bid  = blockIdx.x;
    const int tid_ = (bid & 7) * 196 + (bid >> 3);
    const int nt   = tid_ & 1;        // o-tile (0/1)
    const int mt   = tid_ >> 1;       // sp-tile (0..783)
    const int o0   = nt * 128;
    const int m0   = mt * 128;

    // ---- staging: thread t -> row (t>>2)+q*64, phys slot (t&3) sources
    // global slot (t&3)^(row&3); row&3 == (t>>2)&3 (q*64 preserves low bits)
    const int srow = t >> 2;
    const int sg   = ((t & 3) ^ (srow & 3)) * 16;   // source slot byte offset
    const unsigned char* w_g0 = WT4 + (size_t)(o0 + srow) * WROWB + sg;
    const unsigned char* w_g1 = w_g0 + (size_t)64 * WROWB;
    const unsigned char* a_g0;
    const unsigned char* a_g1;
    {
        int m, ni, sp, h, w;
        m = m0 + srow;
        ni = m / SPATIAL; sp = m - ni * SPATIAL; h = sp / HWDIM; w = sp - h * HWDIM;
        a_g0 = xb4 + ((size_t)(ni * HPAD + h) * HPAD + w) * ROWB + sg;
        m = m0 + srow + 64;
        ni = m / SPATIAL; sp = m - ni * SPATIAL; h = sp / HWDIM; w = sp - h * HWDIM;
        a_g1 = xb4 + ((size_t)(ni * HPAD + h) * HPAD + w) * ROWB + sg;
    }
    char* dstT = lds + t * 16;

    f32x16 acc[2][2];
    #pragma unroll
    for (int i = 0; i < 2; ++i)
        #pragma unroll
        for (int j = 0; j < 2; ++j)
            acc[i][j] = (f32x16){0.f,0.f,0.f,0.f,0.f,0.f,0.f,0.f,
                                 0.f,0.f,0.f,0.f,0.f,0.f,0.f,0.f};

    // ---- read-side: wave (wv&1)=o-half, (wv>>1)=sp-half; lane row l31
    const int l31 = lane & 31;
    const int l5  = lane >> 5;
    const int rsw = l31 & 3;                       // row&3 for swizzle
    const int wbase = ((wv & 1) * 64 + l31) * 64;          // W row byte base
    const int abase = 8192 + ((wv >> 1) * 64 + l31) * 64;  // A row byte base

    // STAGE step S: tap = S>>1, chunk = S&1 (64B half of the 128B row)
    #define STAGE(S, B)                                                     \
    {                                                                       \
        const int s_ = (S);                                                 \
        const int tap = s_ >> 1;                                            \
        const int kh = tap / 3, kw = tap - kh * 3;                          \
        const int ch = (s_ & 1) * 64;                                       \
        const int aoff = (kh * HPAD + kw) * ROWB + ch;                      \
        const int woff = tap * 128 + ch;                                    \
        char* d = dstT + (B) * LDSBUF;                                      \
        GLD16(w_g0 + woff, d);                                              \
        GLD16(w_g1 + woff, d + 4096);                                       \
        GLD16(a_g0 + aoff, d + 8192);                                       \
        GLD16(a_g1 + aoff, d + 12288);                                      \
    }

    i32x8 wf[2] = {};
    i32x8 xf[2] = {};

    // prologue: stage 0,1 (8 loads); wait stage 0 (4 younger); barrier
    STAGE(0, 0);
    STAGE(1, 1);
    asm volatile("s_waitcnt vmcnt(4)\n\ts_barrier" ::: "memory");

    #pragma unroll
    for (int s = 0; s < NSTEP; ++s) {
        const char* Wb = lds + (s % 3) * LDSBUF;

        if (s + 2 < NSTEP) STAGE(s + 2, (s + 2) % 3);   // 4 DMA

        #pragma unroll
        for (int ks = 0; ks < 2; ++ks) {
            const int slot = (((ks << 1) | l5) ^ rsw) << 4;
            *(i32x4*)&wf[0] = *(const i32x4*)(Wb + wbase + slot);
            *(i32x4*)&wf[1] = *(const i32x4*)(Wb + wbase + 2048 + slot);
            *(i32x4*)&xf[0] = *(const i32x4*)(Wb + abase + slot);
            *(i32x4*)&xf[1] = *(const i32x4*)(Wb + abase + 2048 + slot);

            __builtin_amdgcn_s_setprio(1);
            #pragma unroll
            for (int i = 0; i < 2; ++i)
                #pragma unroll
                for (int j = 0; j < 2; ++j)
                    acc[i][j] = __builtin_amdgcn_mfma_scale_f32_32x32x64_f8f6f4(
                        wf[i], xf[j], acc[i][j], 4, 4, 0, 127, 0, 127);
            __builtin_amdgcn_s_setprio(0);
        }

        // end-of-step: stage s+1 retired (4 younger DMA), reads drained, barrier
        if (s < NSTEP - 2)
            asm volatile("s_waitcnt vmcnt(4) lgkmcnt(0)\n\ts_barrier" ::: "memory");
        else if (s == NSTEP - 2)
            asm volatile("s_waitcnt vmcnt(0) lgkmcnt(0)\n\ts_barrier" ::: "memory");
    }

    // ---- epilogue: out[n][o][h][w] = acc * alpha[o] ----
    // 32x32 D frag: col(sp) = lane&31, row(o) = (reg&3)+8*(reg>>2)+4*(lane>>5)
    const int ob0 = o0 + (wv & 1) * 64;
    const int mb0 = m0 + (wv >> 1) * 64;
    #pragma unroll
    for (int j = 0; j < 2; ++j) {
        int m  = mb0 + j * 32 + l31;
        int ni = m / SPATIAL;
        int sp = m - ni * SPATIAL;
        long base = (long)ni * (OCH * SPATIAL) + sp;
        #pragma unroll
        for (int i = 0; i < 2; ++i) {
            #pragma unroll
            for (int r = 0; r < 16; ++r) {
                int o = ob0 + i * 32 + (r & 3) + 8 * (r >> 2) + 4 * l5;
                out[base + (long)o * SPATIAL] = acc[i][j][r] * alpha[o];
            }
        }
    }
    #undef STAGE
}

// =====================================================================
extern "C" void kernel_launch(void* const* d_in, const int* in_sizes, int n_in,
                              void* d_out, int out_size, void* d_ws, size_t ws_size,
                              hipStream_t stream) {
    const float* x  = (const float*)d_in[0];
    const float* w1 = (const float*)d_in[1];
    const float* w2 = (const float*)d_in[2];
    float* out = (float*)d_out;

    char* ws = (char*)d_ws;
    unsigned char* xb4   = (unsigned char*)ws;
    unsigned char* WT4   = (unsigned char*)(ws + WT4_OFF);
    float*         alpha = (float*)(ws + ALPHA_OFF);

    hipLaunchKernelGGL(prep_weights, dim3(OCH), dim3(256), 0, stream, w1, w2, WT4, alpha);
    hipLaunchKernelGGL(binarize_kernel, dim3(NIMG * HPAD), dim3(256), 0, stream, x, xb4);
    hipLaunchKernelGGL(conv_kernel, dim3((M_TOT / 128) * 2), dim3(256), 0, stream,
                       xb4, WT4, alpha, out);
}